// Round 2
// baseline (291.266 us; speedup 1.0000x reference)
//
#include <hip/hip_runtime.h>
#include <hip/hip_bf16.h>
#include <stdint.h>

typedef __attribute__((ext_vector_type(8))) __bf16 bf16x8;
typedef __attribute__((ext_vector_type(4))) float f32x4_t;
typedef __attribute__((ext_vector_type(2))) unsigned int u32x2;
typedef unsigned int uint32;

#define EPSC 1e-6f

__device__ __forceinline__ unsigned short f2bf(float x){
  return __builtin_bit_cast(unsigned short, (__bf16)x);
}
__device__ __forceinline__ uint32 pk2(float a, float b){
  return (uint32)f2bf(a) | ((uint32)f2bf(b) << 16);
}

// ---------------- prep: WT[f][c] = bf16(W[c][f]) ----------------
__global__ void prep_wt(const float* __restrict__ W, unsigned short* __restrict__ WT){
  int c = blockIdx.x;   // 0..255
  int f = threadIdx.x;  // 0..255
  WT[(size_t)f*256 + c] = f2bf(W[(size_t)c*256 + f]);
}

// ---------------- deg: dv (row sums -> rsqrt) and de (col sums, atomics) ----------------
// grid 512, block 256; each block: 32 rows of H
__global__ void deg_kernel(const float* __restrict__ H, float* __restrict__ dvs, float* __restrict__ de){
  __shared__ float sm[32*256];
  const int t = threadIdx.x;
  const int n0 = blockIdx.x * 32;
  const int r = t >> 3, q = t & 7;
  float rp = 0.f;
  for (int ch = 0; ch < 16; ++ch){
    const float* base = H + (size_t)(n0 + r)*4096 + ch*256;
    #pragma unroll
    for (int i = 0; i < 8; ++i){
      f32x4_t v = *(const f32x4_t*)(base + q*4 + 32*i);
      rp += v[0]+v[1]+v[2]+v[3];
      *(f32x4_t*)(sm + r*256 + q*4 + 32*i) = v;
    }
    __syncthreads();
    float cs = 0.f;
    #pragma unroll 8
    for (int rr = 0; rr < 32; ++rr) cs += sm[rr*256 + t];
    atomicAdd(de + ch*256 + t, cs);
    __syncthreads();
  }
  sm[t] = rp;
  __syncthreads();
  if (t < 32){
    float s = 0.f;
    #pragma unroll
    for (int j = 0; j < 8; ++j) s += sm[t*8 + j];
    dvs[n0 + t] = rsqrtf(s + EPSC);
  }
}

// ---------------- unified MFMA GEMM ----------------
// C[M,256] = A[M,K] @ BT[256,K]^T, A f32 (converted to bf16 in staging), BT bf16.
// Block: 256 thr = 4 waves; tile BM=64 x BN=256, BK=32.
// TRANS=0: A row-major k-contiguous. TRANS=1: A-logical = Asrc^T (Asrc = H[n][e], m=e, k=n).
// EPI=0: atomicAdd into Cacc (f32, split-K). EPI=1: scale rows by dvs, store bf16 transposed to XsT[f][n] (stride 16384).
template<int TRANS, int EPI, int LDA, int KB, int NMT, int CHUNK>
__global__ __launch_bounds__(256, 3)
void gemm_k(const float* __restrict__ Asrc, const unsigned short* __restrict__ BT,
            float* __restrict__ Cacc, const float* __restrict__ dvs, unsigned short* __restrict__ XsT)
{
  constexpr int NIT = CHUNK / 32;
  constexpr int ASZ = 64*32*2;     // 4096 B per A buffer
  constexpr int BSZ = 256*32*2;    // 16384 B per B buffer
  __shared__ __align__(16) char lds[2*ASZ + 2*BSZ];

  const int t = threadIdx.x;
  const int lane = t & 63;
  const int w = t >> 6;            // 0..3 (wave = one 64-col slice of F)
  const int mt = blockIdx.x % NMT;
  const int s  = blockIdx.x / NMT;
  const int k0 = s * CHUNK;

  // staging coords
  const int st_r  = t >> 2, st_cq = t & 3;     // straight: row 0..63, col-quarter
  const int tr_nl = t >> 3, tr_fq = t & 7;     // trans: n row 0..31, e-f4 phase

  f32x4_t acc[4][4] = {};
  f32x4_t pa[2];

  auto loadA = [&](int it){
    if (TRANS == 0){
      const float* p = Asrc + (size_t)(mt*64 + st_r)*LDA + k0 + it*32 + st_cq*4;
      pa[0] = *(const f32x4_t*)(p);
      pa[1] = *(const f32x4_t*)(p + 16);
    } else {
      const float* p = Asrc + (size_t)(k0 + it*32 + tr_nl)*LDA + mt*64 + tr_fq*4;
      pa[0] = *(const f32x4_t*)(p);
      pa[1] = *(const f32x4_t*)(p + 32);
    }
  };

  auto gllB = [&](int it, int buf){
    char* bb = lds + 2*ASZ + buf*BSZ;
    const int kcur = k0 + it*32;
    const int swzh = ((lane & 3) ^ ((lane >> 2) & 3)) << 3;  // halfword offset => 16B-piece XOR swizzle
    #pragma unroll
    for (int j = 0; j < 4; ++j){
      int chunk = w*4 + j;                       // 0..15, each = 16 rows (1KB)
      int frow = chunk*16 + (lane >> 2);
      const unsigned short* src = BT + (size_t)frow*KB + kcur + swzh;
      __builtin_amdgcn_global_load_lds((const __attribute__((address_space(1))) void*)src,
                                       (__attribute__((address_space(3))) void*)(bb + chunk*1024),
                                       16, 0, 0);
    }
  };

  auto stageA = [&](int buf){
    char* ab = lds + buf*ASZ;
    if (TRANS == 0){
      #pragma unroll
      for (int i = 0; i < 2; ++i){
        int f4 = st_cq + 4*i;
        uint32 lo = pk2(pa[i][0], pa[i][1]);
        uint32 hi = pk2(pa[i][2], pa[i][3]);
        *(u32x2*)(ab + st_r*64 + ((f4*8) ^ ((st_r & 3) << 4))) = u32x2{lo, hi};
      }
    } else {
      const int np = tr_nl >> 1;
      const bool odd = tr_nl & 1;
      #pragma unroll
      for (int i = 0; i < 2; ++i){
        int E = (tr_fq + 8*i) * 4;               // e-row base, 0..60
        uint32 my01 = pk2(pa[i][0], pa[i][1]);
        uint32 my23 = pk2(pa[i][2], pa[i][3]);
        uint32 pp01 = __shfl_xor((int)my01, 8);
        uint32 pp23 = __shfl_xor((int)my23, 8);
        uint32 lo = odd ? pp23 : my01;           // lo-halves = even-n values
        uint32 hi = odd ? my23 : pp01;           // hi-halves = odd-n values
        uint32 w0 = (lo & 0xFFFFu) | (hi << 16);
        uint32 w1 = (lo >> 16) | (hi & 0xFFFF0000u);
        int e0 = E + (odd ? 2 : 0);
        *(uint32*)(ab + (e0    )*64 + (((np*4)) ^ (((e0    ) & 3) << 4))) = w0;
        *(uint32*)(ab + (e0 + 1)*64 + (((np*4)) ^ (((e0 + 1) & 3) << 4))) = w1;
      }
    }
  };

  auto compute = [&](int buf){
    const char* ab = lds + buf*ASZ;
    const char* bb = lds + 2*ASZ + buf*BSZ;
    const int kswz = (((lane >> 4) ^ (lane & 3)) << 4);
    bf16x8 af[4], bfr[4];
    #pragma unroll
    for (int mi = 0; mi < 4; ++mi){
      int row = mi*16 + (lane & 15);
      af[mi] = *(const bf16x8*)(ab + row*64 + kswz);
    }
    #pragma unroll
    for (int fi = 0; fi < 4; ++fi){
      int row = w*64 + fi*16 + (lane & 15);
      bfr[fi] = *(const bf16x8*)(bb + row*64 + kswz);
    }
    #pragma unroll
    for (int mi = 0; mi < 4; ++mi){
      #pragma unroll
      for (int fi = 0; fi < 4; ++fi){
        acc[mi][fi] = __builtin_amdgcn_mfma_f32_16x16x32_bf16(af[mi], bfr[fi], acc[mi][fi], 0, 0, 0);
      }
    }
  };

  // prologue
  loadA(0);
  gllB(0, 0);
  stageA(0);
  __syncthreads();

  int cur = 0;
  #pragma unroll 1
  for (int it = 0; it < NIT; ++it){
    if (it + 1 < NIT){
      loadA(it + 1);
      gllB(it + 1, cur ^ 1);
    }
    compute(cur);
    if (it + 1 < NIT) stageA(cur ^ 1);
    __syncthreads();
    cur ^= 1;
  }

  // epilogue
  if (EPI == 0){
    #pragma unroll
    for (int mi = 0; mi < 4; ++mi){
      int row0 = mt*64 + mi*16 + ((lane >> 4) * 4);
      #pragma unroll
      for (int fi = 0; fi < 4; ++fi){
        int f = w*64 + fi*16 + (lane & 15);
        #pragma unroll
        for (int r = 0; r < 4; ++r)
          atomicAdd(Cacc + (size_t)(row0 + r)*256 + f, acc[mi][fi][r]);
      }
    }
  } else {
    #pragma unroll
    for (int mi = 0; mi < 4; ++mi){
      int n0 = mt*64 + mi*16 + ((lane >> 4) * 4);
      float d0 = dvs[n0], d1 = dvs[n0+1], d2 = dvs[n0+2], d3 = dvs[n0+3];
      #pragma unroll
      for (int fi = 0; fi < 4; ++fi){
        int f = w*64 + fi*16 + (lane & 15);
        uint32 lo = pk2(acc[mi][fi][0]*d0, acc[mi][fi][1]*d1);
        uint32 hi = pk2(acc[mi][fi][2]*d2, acc[mi][fi][3]*d3);
        *(u32x2*)(XsT + (size_t)f*16384 + n0) = u32x2{lo, hi};
      }
    }
  }
}

// ---------------- mid: T1sT[f][e] = bf16(T1acc[e][f] / (de[e]+eps)) ----------------
// grid 1024, block 256 (f = tid, 4 e-rows per block)
__global__ void mid_kernel(const float* __restrict__ T1acc, const float* __restrict__ de,
                           unsigned short* __restrict__ T1sT){
  int f = threadIdx.x;
  int e0 = blockIdx.x * 4;
  float v[4];
  #pragma unroll
  for (int r = 0; r < 4; ++r){
    float di = 1.f / (de[e0 + r] + EPSC);
    v[r] = T1acc[(size_t)(e0 + r)*256 + f] * di;
  }
  uint32 lo = pk2(v[0], v[1]);
  uint32 hi = pk2(v[2], v[3]);
  *(u32x2*)(T1sT + (size_t)f*4096 + e0) = u32x2{lo, hi};
}

// ---------------- fin: out[n][f] = relu(dvs[n] * out[n][f]) in place, f32 ----------------
// grid 2048, block 256, 8 elems/thread
__global__ void fin_kernel(float* __restrict__ out, const float* __restrict__ dvs){
  int gid = blockIdx.x*256 + threadIdx.x;
  int n = gid >> 5;
  int f0 = (gid & 31) * 8;
  size_t off = (size_t)n*256 + f0;
  f32x4_t a = *(const f32x4_t*)(out + off);
  f32x4_t b = *(const f32x4_t*)(out + off + 4);
  float d = dvs[n];
  f32x4_t oa, ob;
  oa[0] = fmaxf(a[0]*d, 0.f); oa[1] = fmaxf(a[1]*d, 0.f);
  oa[2] = fmaxf(a[2]*d, 0.f); oa[3] = fmaxf(a[3]*d, 0.f);
  ob[0] = fmaxf(b[0]*d, 0.f); ob[1] = fmaxf(b[1]*d, 0.f);
  ob[2] = fmaxf(b[2]*d, 0.f); ob[3] = fmaxf(b[3]*d, 0.f);
  *(f32x4_t*)(out + off) = oa;
  *(f32x4_t*)(out + off + 4) = ob;
}

extern "C" void kernel_launch(void* const* d_in, const int* in_sizes, int n_in,
                              void* d_out, int out_size, void* d_ws, size_t ws_size,
                              hipStream_t stream) {
  const float* emb = (const float*)d_in[0];   // [16384,256]
  const float* H   = (const float*)d_in[1];   // [16384,4096]
  const float* W   = (const float*)d_in[2];   // [256,256]
  float* out = (float*)d_out;                 // f32 [16384,256]

  char* ws = (char*)d_ws;
  float*          dvs   = (float*)(ws + 0);                 // 65536 B
  float*          de    = (float*)(ws + 65536);             // 16384 B
  unsigned short* WT    = (unsigned short*)(ws + 81920);    // 131072 B
  unsigned short* XsT   = (unsigned short*)(ws + 212992);   // 8388608 B [256][16384]
  float*          T1acc = (float*)(ws + 8601600);           // 4194304 B [4096][256]
  unsigned short* T1sT  = (unsigned short*)(ws + 12795904); // 2097152 B [256][4096]
  // total ws usage: 14,893,056 B

  hipMemsetAsync(de, 0, 4096*4, stream);
  hipMemsetAsync(T1acc, 0, (size_t)4096*256*4, stream);
  hipMemsetAsync(out, 0, (size_t)16384*256*4, stream);

  prep_wt<<<256, 256, 0, stream>>>(W, WT);
  deg_kernel<<<512, 256, 0, stream>>>(H, dvs, de);

  // X: XsT[f][n] = bf16(dvs[n] * (emb@W)[n][f]);  M=16384 (n), K=256 (c)
  gemm_k<0, 1, 256, 256, 256, 256><<<256, 256, 0, stream>>>(emb, WT, nullptr, dvs, XsT);

  // GEMM1: T1acc[e][f] += sum_n H[n][e]*Xs[n][f];  M=4096 (e), K=16384 (n), split-K=8
  gemm_k<1, 0, 4096, 16384, 64, 2048><<<512, 256, 0, stream>>>(H, XsT, T1acc, nullptr, nullptr);

  mid_kernel<<<1024, 256, 0, stream>>>(T1acc, de, T1sT);

  // GEMM2: out[n][f] += sum_e H[n][e]*T1s[e][f];  M=16384 (n), K=4096 (e), split-K=2, f32 atomics into d_out
  gemm_k<0, 0, 4096, 4096, 256, 2048><<<512, 256, 0, stream>>>(H, T1sT, out, nullptr, nullptr);

  // out = relu(dvs[n] * out) in place
  fin_kernel<<<2048, 256, 0, stream>>>(out, dvs);
}